// Round 1
// 1546.780 us; speedup vs baseline: 1.0310x; 1.0310x over previous
//
#include <hip/hip_runtime.h>
#include <math.h>

// Problem constants: B=1, T=4096, C=1024, H=16, dk=64, FF=4096
typedef unsigned short u16;
typedef unsigned int u32;
typedef __attribute__((ext_vector_type(8))) short bf16x8;  // MFMA A/B frag (8 bf16)
typedef __attribute__((ext_vector_type(4))) float f32x4;   // MFMA C/D frag

#define MFMA16(a, b, c) __builtin_amdgcn_mfma_f32_16x16x32_bf16((a), (b), (c), 0, 0, 0)

__device__ __forceinline__ u16 f2bf(float f) {
  u32 u = __float_as_uint(f);
  return (u16)((u + 0x7fffu + ((u >> 16) & 1u)) >> 16);  // RNE
}

typedef const __attribute__((address_space(1))) u32* gas_t;
typedef __attribute__((address_space(3))) u32* las_t;
__device__ __forceinline__ void gl_lds16(const u16* g, u16* l) {
  // async global->LDS, 16B per lane; LDS dest = wave-uniform base + lane*16
  __builtin_amdgcn_global_load_lds((gas_t)g, (las_t)l, 16, 0, 0);
}

// ---------------- fp32 -> bf16 convert, all 4 weight matrices in one launch ----------------
// ranges (blocks of 256 float4): [0,3072) w_qkv, [3072,4096) w_out, [4096,8192) w1, [8192,12288) w2
__global__ __launch_bounds__(256) void cvt_all_kernel(const float* __restrict__ s0, u16* __restrict__ d0,
                                                      const float* __restrict__ s1, u16* __restrict__ d1,
                                                      const float* __restrict__ s2, u16* __restrict__ d2,
                                                      const float* __restrict__ s3, u16* __restrict__ d3) {
  int blk = blockIdx.x, t = threadIdx.x;
  const float* src;
  u16* dst;
  int i;
  if (blk < 3072)      { src = s0; dst = d0; i = blk * 256 + t; }
  else if (blk < 4096) { src = s1; dst = d1; i = (blk - 3072) * 256 + t; }
  else if (blk < 8192) { src = s2; dst = d2; i = (blk - 4096) * 256 + t; }
  else                 { src = s3; dst = d3; i = (blk - 8192) * 256 + t; }
  float4 v = ((const float4*)src)[i];
  ushort4 o;
  o.x = f2bf(v.x); o.y = f2bf(v.y); o.z = f2bf(v.z); o.w = f2bf(v.w);
  ((ushort4*)dst)[i] = o;
}

// ---------------- LayerNorm (fp32 in, bf16 out), one block per row of 1024 ----------------
__global__ __launch_bounds__(256) void ln_kernel(const float* __restrict__ x,
                                                 const float* __restrict__ g,
                                                 const float* __restrict__ b,
                                                 u16* __restrict__ out) {
  int row = blockIdx.x, tid = threadIdx.x;
  float4 v = ((const float4*)(x + (size_t)row * 1024))[tid];
  float s = v.x + v.y + v.z + v.w;
  float s2 = v.x * v.x + v.y * v.y + v.z * v.z + v.w * v.w;
  for (int off = 32; off; off >>= 1) { s += __shfl_xor(s, off); s2 += __shfl_xor(s2, off); }
  __shared__ float ps[4], ps2[4];
  int wave = tid >> 6;
  if ((tid & 63) == 0) { ps[wave] = s; ps2[wave] = s2; }
  __syncthreads();
  float fs = ps[0] + ps[1] + ps[2] + ps[3];
  float fs2 = ps2[0] + ps2[1] + ps2[2] + ps2[3];
  float mu = fs * (1.0f / 1024.0f);
  float var = fs2 * (1.0f / 1024.0f) - mu * mu;
  float rs = rsqrtf(var + 1e-5f);
  float4 gv = ((const float4*)g)[tid];
  float4 bv = ((const float4*)b)[tid];
  ushort4 o;
  o.x = f2bf((v.x - mu) * rs * gv.x + bv.x);
  o.y = f2bf((v.y - mu) * rs * gv.y + bv.y);
  o.z = f2bf((v.z - mu) * rs * gv.z + bv.z);
  o.w = f2bf((v.w - mu) * rs * gv.w + bv.w);
  ((ushort4*)(out + (size_t)row * 1024))[tid] = o;
}

// ---------------- V transpose: qkv[t][2048+h*64+d] -> vt[(h*64+d)][t] ----------------
__global__ __launch_bounds__(256) void vtrans_kernel(const u16* __restrict__ qkv,
                                                     u16* __restrict__ vt) {
  const int tt = blockIdx.x, h = blockIdx.y;
  __shared__ u16 tile[64 * 68];  // stride 68 (136B): 8B-aligned rows, breaks worst conflicts
  const int tid = threadIdx.x;
#pragma unroll
  for (int i = 0; i < 2; i++) {
    int c = i * 256 + tid;
    int trow = c >> 3, dc = c & 7;
    const u16* src = qkv + (size_t)(tt * 64 + trow) * 3072 + 2048 + h * 64 + dc * 8;
    uint4 v = *(const uint4*)src;
    *(uint2*)&tile[trow * 68 + dc * 8] = make_uint2(v.x, v.y);
    *(uint2*)&tile[trow * 68 + dc * 8 + 4] = make_uint2(v.z, v.w);
  }
  __syncthreads();
#pragma unroll
  for (int i = 0; i < 2; i++) {
    int c = i * 256 + tid;
    int d = c >> 3, tc = c & 7;
    ushort4 o0, o1;
    o0.x = tile[(tc * 8 + 0) * 68 + d]; o0.y = tile[(tc * 8 + 1) * 68 + d];
    o0.z = tile[(tc * 8 + 2) * 68 + d]; o0.w = tile[(tc * 8 + 3) * 68 + d];
    o1.x = tile[(tc * 8 + 4) * 68 + d]; o1.y = tile[(tc * 8 + 5) * 68 + d];
    o1.z = tile[(tc * 8 + 6) * 68 + d]; o1.w = tile[(tc * 8 + 7) * 68 + d];
    u16* dst = vt + (size_t)(h * 64 + d) * 4096 + tt * 64 + tc * 8;
    *(ushort4*)dst = o0;
    *(ushort4*)(dst + 4) = o1;
  }
}

// ---------------- bf16 GEMM body: C[M,N] = A[M,K] @ B[N,K]^T + bias (+resid) ----------------
// EPI: 0 = bf16 out (bias), 1 = fp32 out (bias + fp32 residual), 2 = bf16 out (bias + exact GELU)
template <int EPI>
__device__ __forceinline__ void gemm_body(const u16* __restrict__ A, const u16* __restrict__ B,
                                          const float* __restrict__ bias,
                                          const float* __restrict__ resid,
                                          void* __restrict__ Cout, int M, int N, int K,
                                          int bxi, int byi, u16* As, u16* Bs) {
  // As/Bs: 128*32 u16 each, XOR-swizzled 16B chunks: sc = row*4 + (q ^ ((row>>1)&3))
  const int tid = threadIdx.x, lane = tid & 63, wave = tid >> 6;
  const int wr = wave >> 1, wc = wave & 1;
  const int bm = byi * 128, bn = bxi * 128;
  const int r = lane & 15, qd = lane >> 4;
  (void)M;

  const u16 *ag[2], *bg[2];
  u16 *al[2], *bl[2];
#pragma unroll
  for (int i = 0; i < 2; i++) {
    int C0 = wave * 128 + i * 64;
    int sc = C0 + lane;
    int row = sc >> 2;
    int q = (sc & 3) ^ ((row >> 1) & 3);
    ag[i] = A + (size_t)(bm + row) * K + q * 8;
    al[i] = &As[C0 * 8];
    bg[i] = B + (size_t)(bn + row) * K + q * 8;
    bl[i] = &Bs[C0 * 8];
  }
  const int swz = (r >> 1) & 3;
  f32x4 acc[4][4] = {};
  for (int k0 = 0; k0 < K; k0 += 32) {
#pragma unroll
    for (int i = 0; i < 2; i++) { gl_lds16(ag[i] + k0, al[i]); gl_lds16(bg[i] + k0, bl[i]); }
    __syncthreads();
    bf16x8 af[4], bfr[4];
#pragma unroll
    for (int mi = 0; mi < 4; mi++) {
      int row = wr * 64 + mi * 16 + r;
      af[mi] = *(const bf16x8*)&As[(row * 4 + (qd ^ swz)) * 8];
    }
#pragma unroll
    for (int ni = 0; ni < 4; ni++) {
      int row = wc * 64 + ni * 16 + r;
      bfr[ni] = *(const bf16x8*)&Bs[(row * 4 + (qd ^ swz)) * 8];
    }
#pragma unroll
    for (int mi = 0; mi < 4; mi++)
#pragma unroll
      for (int ni = 0; ni < 4; ni++)
        acc[mi][ni] = MFMA16(af[mi], bfr[ni], acc[mi][ni]);
    __syncthreads();
  }
  // epilogue: C/D layout row = qd*4+reg (+16*mi), col = r (+16*ni)
  const int crow0 = bm + wr * 64 + qd * 4;
  const int ccol0 = bn + wc * 64 + r;
#pragma unroll
  for (int ni = 0; ni < 4; ni++) {
    int col = ccol0 + ni * 16;
    float bv = bias[col];
#pragma unroll
    for (int mi = 0; mi < 4; mi++) {
#pragma unroll
      for (int rg = 0; rg < 4; rg++) {
        int row = crow0 + mi * 16 + rg;
        float v = acc[mi][ni][rg] + bv;
        if (EPI == 1) v += resid[(size_t)row * N + col];
        if (EPI == 2) v = 0.5f * v * (1.0f + erff(v * 0.70710678118654752f));
        if (EPI == 1) ((float*)Cout)[(size_t)row * N + col] = v;
        else ((u16*)Cout)[(size_t)row * N + col] = f2bf(v);
      }
    }
  }
}

template <int EPI>
__global__ __launch_bounds__(256, 2) void gemm_bf16(const u16* __restrict__ A,
                                                    const u16* __restrict__ B,
                                                    const float* __restrict__ bias,
                                                    const float* __restrict__ resid,
                                                    void* __restrict__ Cout,
                                                    int M, int N, int K) {
  __shared__ u16 As[128 * 32];
  __shared__ u16 Bs[128 * 32];
  gemm_body<EPI>(A, B, bias, resid, Cout, M, N, K, blockIdx.x, blockIdx.y, As, Bs);
}

// ---------------- attention pass 1: flash fwd (S^T = K·Q^T), emits O, m, l ----------------
__global__ __launch_bounds__(256, 2) void attn_pass1(const u16* __restrict__ qkv,
                                                     const u16* __restrict__ vt,
                                                     u16* __restrict__ aout,
                                                     float* __restrict__ mstat,
                                                     float* __restrict__ lstat) {
  const int qb = blockIdx.x, h = blockIdx.y;
  const int tid = threadIdx.x, lane = tid & 63, wave = tid >> 6;
  const int r = lane & 15, qd = lane >> 4;
  __shared__ u16 Qs[128 * 64];   // sc = row*8 + (q ^ (row&7))
  __shared__ u16 Ks[128 * 64];
  __shared__ u16 Vts[64 * 128];  // sc = d*16 + (qq ^ (d&15))
  __shared__ u16 Ps[128 * 128];  // [q][kpos], sc = q*16 + (qq ^ (q&15))

  // stage Q once
#pragma unroll
  for (int i = 0; i < 4; i++) {
    int C0 = wave * 256 + i * 64;
    int sc = C0 + lane;
    int row = sc >> 3;
    int q = (sc & 7) ^ (row & 7);
    gl_lds16(qkv + (size_t)(qb * 128 + row) * 3072 + h * 64 + q * 8, &Qs[C0 * 8]);
  }
  const u16 *kg[4], *vg[4];
  u16 *kl[4], *vl[4];
#pragma unroll
  for (int i = 0; i < 4; i++) {
    int C0 = wave * 256 + i * 64;
    int sc = C0 + lane;
    int row = sc >> 3;
    int q = (sc & 7) ^ (row & 7);
    kg[i] = qkv + (size_t)row * 3072 + 1024 + h * 64 + q * 8;
    kl[i] = &Ks[C0 * 8];
    int d = sc >> 4;
    int qq = (sc & 15) ^ (d & 15);
    vg[i] = vt + (size_t)(h * 64 + d) * 4096 + qq * 8;
    vl[i] = &Vts[C0 * 8];
  }
  __syncthreads();  // Qs ready
  bf16x8 qf[2][2];
#pragma unroll
  for (int ni = 0; ni < 2; ni++)
#pragma unroll
    for (int kk = 0; kk < 2; kk++) {
      int qrow = wave * 32 + ni * 16 + r;
      int qq = kk * 4 + qd;
      qf[ni][kk] = *(const bf16x8*)&Qs[(qrow * 8 + (qq ^ (qrow & 7))) * 8];
    }
  f32x4 ot[4][2] = {};
  float m_run[2] = {-INFINITY, -INFINITY};
  float l_run[2] = {0.f, 0.f};

  for (int kb = 0; kb <= qb; kb++) {
#pragma unroll
    for (int i = 0; i < 4; i++) {
      gl_lds16(kg[i] + (size_t)kb * 128 * 3072, kl[i]);
      gl_lds16(vg[i] + kb * 128, vl[i]);
    }
    __syncthreads();
    // S^T[kpos][q] = K·Q^T
    f32x4 st[8][2] = {};
#pragma unroll
    for (int kk = 0; kk < 2; kk++) {
      bf16x8 kf[8];
#pragma unroll
      for (int mi = 0; mi < 8; mi++) {
        int krow = mi * 16 + r;
        int qq = kk * 4 + qd;
        kf[mi] = *(const bf16x8*)&Ks[(krow * 8 + (qq ^ (krow & 7))) * 8];
      }
#pragma unroll
      for (int mi = 0; mi < 8; mi++)
#pragma unroll
        for (int ni = 0; ni < 2; ni++)
          st[mi][ni] = MFMA16(kf[mi], qf[ni][kk], st[mi][ni]);
    }
    if (kb == qb) {  // causal mask inside diagonal block
#pragma unroll
      for (int mi = 0; mi < 8; mi++) {
        int k0 = mi * 16 + qd * 4;
#pragma unroll
        for (int ni = 0; ni < 2; ni++) {
          int qloc = wave * 32 + ni * 16 + r;
#pragma unroll
          for (int rg = 0; rg < 4; rg++)
            if (k0 + rg > qloc) st[mi][ni][rg] = -INFINITY;
        }
      }
    }
    float mb[2], alpha[2];
#pragma unroll
    for (int ni = 0; ni < 2; ni++) {
      float mx = -INFINITY;
#pragma unroll
      for (int mi = 0; mi < 8; mi++)
        mx = fmaxf(mx, fmaxf(fmaxf(st[mi][ni][0], st[mi][ni][1]),
                             fmaxf(st[mi][ni][2], st[mi][ni][3])));
      mx = fmaxf(mx, __shfl_xor(mx, 16));
      mx = fmaxf(mx, __shfl_xor(mx, 32));
      float mn = fmaxf(m_run[ni], mx);
      alpha[ni] = __expf((m_run[ni] - mn) * 0.125f);  // m kept in unscaled units
      m_run[ni] = mn;
      mb[ni] = mn;
    }
#pragma unroll
    for (int ni = 0; ni < 2; ni++) {
      int qrow = wave * 32 + ni * 16 + r;
      float ls = 0.f;
#pragma unroll
      for (int mi = 0; mi < 8; mi++) {
        float p0 = __expf((st[mi][ni][0] - mb[ni]) * 0.125f);
        float p1 = __expf((st[mi][ni][1] - mb[ni]) * 0.125f);
        float p2 = __expf((st[mi][ni][2] - mb[ni]) * 0.125f);
        float p3 = __expf((st[mi][ni][3] - mb[ni]) * 0.125f);
        ls += p0 + p1 + p2 + p3;
        ushort4 pk;
        pk.x = f2bf(p0); pk.y = f2bf(p1); pk.z = f2bf(p2); pk.w = f2bf(p3);
        int qq = mi * 2 + (qd >> 1);
        int sc = qrow * 16 + (qq ^ (qrow & 15));
        *(ushort4*)&Ps[sc * 8 + (qd & 1) * 4] = pk;
      }
      ls += __shfl_xor(ls, 16);
      ls += __shfl_xor(ls, 32);
      l_run[ni] = l_run[ni] * alpha[ni] + ls;
#pragma unroll
      for (int mi = 0; mi < 4; mi++) ot[mi][ni] = ot[mi][ni] * alpha[ni];
    }
    __syncthreads();  // Ps visible
    // O^T[d][q] += V^T · P^T
#pragma unroll
    for (int kk = 0; kk < 4; kk++) {
      bf16x8 vf[4], pf[2];
#pragma unroll
      for (int mi = 0; mi < 4; mi++) {
        int d = mi * 16 + r;
        int qq = kk * 4 + qd;
        vf[mi] = *(const bf16x8*)&Vts[(d * 16 + (qq ^ (d & 15))) * 8];
      }
#pragma unroll
      for (int ni = 0; ni < 2; ni++) {
        int qrow = wave * 32 + ni * 16 + r;
        int qq = kk * 4 + qd;
        pf[ni] = *(const bf16x8*)&Ps[(qrow * 16 + (qq ^ (qrow & 15))) * 8];
      }
#pragma unroll
      for (int mi = 0; mi < 4; mi++)
#pragma unroll
        for (int ni = 0; ni < 2; ni++)
          ot[mi][ni] = MFMA16(vf[mi], pf[ni], ot[mi][ni]);
    }
    __syncthreads();  // safe to restage K/V/P
  }
#pragma unroll
  for (int ni = 0; ni < 2; ni++) {
    float il = 1.0f / l_run[ni];
    int qg = qb * 128 + wave * 32 + ni * 16 + r;
    if (qd == 0) {
      mstat[h * 4096 + qg] = m_run[ni];
      lstat[h * 4096 + qg] = l_run[ni];
    }
#pragma unroll
    for (int mi = 0; mi < 4; mi++) {
      ushort4 o;
      o.x = f2bf(ot[mi][ni][0] * il);
      o.y = f2bf(ot[mi][ni][1] * il);
      o.z = f2bf(ot[mi][ni][2] * il);
      o.w = f2bf(ot[mi][ni][3] * il);
      *(ushort4*)&aout[(size_t)qg * 1024 + h * 64 + mi * 16 + qd * 4] = o;
    }
  }
}

// ---------------- attention pass 2 body: recompute S^T, write normalized P (and zeros) ----------------
__device__ __forceinline__ void pass2_body(const u16* __restrict__ qkv,
                                           const float* __restrict__ mstat,
                                           const float* __restrict__ lstat,
                                           float* __restrict__ attn, int qb, int h,
                                           u16* Qs, u16* Ks) {
  const int tid = threadIdx.x, lane = tid & 63, wave = tid >> 6;
  const int r = lane & 15, qd = lane >> 4;
#pragma unroll
  for (int i = 0; i < 4; i++) {
    int C0 = wave * 256 + i * 64;
    int sc = C0 + lane;
    int row = sc >> 3;
    int q = (sc & 7) ^ (row & 7);
    gl_lds16(qkv + (size_t)(qb * 128 + row) * 3072 + h * 64 + q * 8, &Qs[C0 * 8]);
  }
  const u16* kg[4];
  u16* kl[4];
#pragma unroll
  for (int i = 0; i < 4; i++) {
    int C0 = wave * 256 + i * 64;
    int sc = C0 + lane;
    int row = sc >> 3;
    int q = (sc & 7) ^ (row & 7);
    kg[i] = qkv + (size_t)row * 3072 + 1024 + h * 64 + q * 8;
    kl[i] = &Ks[C0 * 8];
  }
  __syncthreads();
  bf16x8 qf[2][2];
  float mrow[2], ilrow[2];
#pragma unroll
  for (int ni = 0; ni < 2; ni++) {
#pragma unroll
    for (int kk = 0; kk < 2; kk++) {
      int qrow = wave * 32 + ni * 16 + r;
      int qq = kk * 4 + qd;
      qf[ni][kk] = *(const bf16x8*)&Qs[(qrow * 8 + (qq ^ (qrow & 7))) * 8];
    }
    int qg = qb * 128 + wave * 32 + ni * 16 + r;
    mrow[ni] = mstat[h * 4096 + qg];
    ilrow[ni] = 1.0f / lstat[h * 4096 + qg];
  }
  float* ahead = attn + ((size_t)h << 24);
  for (int kb = 0; kb < 32; kb++) {
    if (kb <= qb) {
#pragma unroll
      for (int i = 0; i < 4; i++) gl_lds16(kg[i] + (size_t)kb * 128 * 3072, kl[i]);
      __syncthreads();
      f32x4 st[8][2] = {};
#pragma unroll
      for (int kk = 0; kk < 2; kk++) {
        bf16x8 kf[8];
#pragma unroll
        for (int mi = 0; mi < 8; mi++) {
          int krow = mi * 16 + r;
          int qq = kk * 4 + qd;
          kf[mi] = *(const bf16x8*)&Ks[(krow * 8 + (qq ^ (krow & 7))) * 8];
        }
#pragma unroll
        for (int mi = 0; mi < 8; mi++)
#pragma unroll
          for (int ni = 0; ni < 2; ni++)
            st[mi][ni] = MFMA16(kf[mi], qf[ni][kk], st[mi][ni]);
      }
#pragma unroll
      for (int ni = 0; ni < 2; ni++) {
        int qloc = wave * 32 + ni * 16 + r;
        size_t rowbase = (size_t)(qb * 128 + qloc) * 4096 + (size_t)kb * 128;
#pragma unroll
        for (int mi = 0; mi < 8; mi++) {
          int k0 = mi * 16 + qd * 4;
          float v0, v1, v2, v3;
          v0 = __expf((st[mi][ni][0] - mrow[ni]) * 0.125f) * ilrow[ni];
          v1 = __expf((st[mi][ni][1] - mrow[ni]) * 0.125f) * ilrow[ni];
          v2 = __expf((st[mi][ni][2] - mrow[ni]) * 0.125f) * ilrow[ni];
          v3 = __expf((st[mi][ni][3] - mrow[ni]) * 0.125f) * ilrow[ni];
          if (kb == qb) {
            if (k0 + 0 > qloc) v0 = 0.f;
            if (k0 + 1 > qloc) v1 = 0.f;
            if (k0 + 2 > qloc) v2 = 0.f;
            if (k0 + 3 > qloc) v3 = 0.f;
          }
          *(float4*)(ahead + rowbase + k0) = make_float4(v0, v1, v2, v3);
        }
      }
      __syncthreads();
    } else {
      // fully-masked tile: write zeros
      size_t base = (size_t)(qb * 128) * 4096 + (size_t)kb * 128;
      float4 z = make_float4(0.f, 0.f, 0.f, 0.f);
#pragma unroll
      for (int i = 0; i < 16; i++) {
        int idx = i * 256 + tid;
        int ql = idx >> 5;
        int ko = (idx & 31) * 4;
        *(float4*)(ahead + base + (size_t)ql * 4096 + ko) = z;
      }
    }
  }
}

// ---------------- fused: FF2 GEMM (compute-bound) || attn pass2 (HBM-write-bound) ----------------
// 768 blocks: idx%3==0 -> one of 256 GEMM blocks (N=1024 -> bx=g&7, by=g>>3)
//             else     -> one of 512 pass2 blocks (qb=p&31, h=p>>5)
// Interleave 1:2 so every CU hosts a mix of compute-bound and write-bound blocks.
__global__ __launch_bounds__(256, 2) void ff2_pass2_fused(
    const u16* __restrict__ A, const u16* __restrict__ B, const float* __restrict__ bias,
    const float* __restrict__ resid, float* __restrict__ Cout,
    const u16* __restrict__ qkv, const float* __restrict__ mstat,
    const float* __restrict__ lstat, float* __restrict__ attn) {
  __shared__ u16 smem[128 * 64 * 2];  // 32 KB union: gemm As/Bs (8KB+8KB) | pass2 Qs/Ks (16KB+16KB)
  int idx = blockIdx.x;
  int q3 = idx / 3, r3 = idx - q3 * 3;
  if (r3 == 0) {
    gemm_body<1>(A, B, bias, resid, (void*)Cout, 4096, 1024, 4096, q3 & 7, q3 >> 3,
                 smem, smem + 128 * 32);
  } else {
    int p = q3 * 2 + (r3 - 1);
    pass2_body(qkv, mstat, lstat, attn, p & 31, p >> 5, smem, smem + 128 * 64);
  }
}

// ---------------- host launch ----------------
extern "C" void kernel_launch(void* const* d_in, const int* in_sizes, int n_in,
                              void* d_out, int out_size, void* d_ws, size_t ws_size,
                              hipStream_t stream) {
  const float* x     = (const float*)d_in[0];
  const float* ln1_g = (const float*)d_in[1];
  const float* ln1_b = (const float*)d_in[2];
  const float* w_qkv = (const float*)d_in[3];
  const float* b_qkv = (const float*)d_in[4];
  const float* w_out = (const float*)d_in[5];
  const float* b_out = (const float*)d_in[6];
  const float* ln2_g = (const float*)d_in[7];
  const float* ln2_b = (const float*)d_in[8];
  const float* w1    = (const float*)d_in[9];
  const float* b1    = (const float*)d_in[10];
  const float* w2    = (const float*)d_in[11];
  const float* b2    = (const float*)d_in[12];
  float* out_x = (float*)d_out;
  float* out_attn = out_x + (size_t)4096 * 1024;

  char* ws = (char*)d_ws;
  size_t off = 0;
  auto alloc = [&](size_t bytes) {
    void* p = ws + off;
    off += (bytes + 255) & ~(size_t)255;
    return p;
  };
  u16* WQKV = (u16*)alloc((size_t)3072 * 1024 * 2);
  u16* WOUT = (u16*)alloc((size_t)1024 * 1024 * 2);
  u16* W1   = (u16*)alloc((size_t)4096 * 1024 * 2);
  u16* W2   = (u16*)alloc((size_t)1024 * 4096 * 2);
  u16* H1   = (u16*)alloc((size_t)8388608);   // ln1 out, bf16 4096x1024
  u16* QKV  = (u16*)alloc((size_t)25165824);  // bf16 4096x3072 (live until fused pass2)
  u16* FF   = (u16*)alloc((size_t)33554432);  // bf16 4096x4096 (de-aliased from QKV)
  u16* VT   = (u16*)alloc((size_t)8388608);
  float* MST = (float*)alloc((size_t)262144);
  float* LST = (float*)alloc((size_t)262144);
  u16* AOUT = (u16*)alloc((size_t)8388608);
  float* X1 = (float*)alloc((size_t)16777216);
  u16* H2  = (u16*)alloc((size_t)8388608);
  (void)ws_size; (void)in_sizes; (void)n_in; (void)out_size;

  cvt_all_kernel<<<12288, 256, 0, stream>>>(w_qkv, WQKV, w_out, WOUT, w1, W1, w2, W2);
  ln_kernel<<<4096, 256, 0, stream>>>(x, ln1_g, ln1_b, H1);
  gemm_bf16<0><<<dim3(24, 32), 256, 0, stream>>>(H1, WQKV, b_qkv, nullptr, QKV, 4096, 3072, 1024);
  vtrans_kernel<<<dim3(64, 16), 256, 0, stream>>>(QKV, VT);
  attn_pass1<<<dim3(32, 16), 256, 0, stream>>>(QKV, VT, AOUT, MST, LST);
  gemm_bf16<1><<<dim3(8, 32), 256, 0, stream>>>(AOUT, WOUT, b_out, x, X1, 4096, 1024, 1024);
  ln_kernel<<<4096, 256, 0, stream>>>(X1, ln2_g, ln2_b, H2);
  gemm_bf16<2><<<dim3(32, 32), 256, 0, stream>>>(H2, W1, b1, nullptr, FF, 4096, 4096, 1024);
  // FF2 (compute-bound) co-scheduled with attention-matrix writeback (HBM-write-bound)
  ff2_pass2_fused<<<768, 256, 0, stream>>>(FF, W2, b2, X1, out_x, QKV, MST, LST, out_attn);
}